// Round 6
// baseline (469.442 us; speedup 1.0000x reference)
//
#include <hip/hip_runtime.h>
#include <math.h>

#define TL 131072

// Output layout (flat f32 element offsets into d_out):
//   recon [TL,16] @0, pred [TL,16] @TL*16, lm_pred [2,TL,8] @TL*32,
//   lv_pred [2,TL,8] @TL*48, Ct [TL,16,8] @TL*64, Ct_1 [TL,16,8] @TL*192
static constexpr size_t OFF_RECON = 0;
static constexpr size_t OFF_PRED  = (size_t)TL * 16;
static constexpr size_t OFF_LMP   = (size_t)TL * 32;
static constexpr size_t OFF_LVP   = (size_t)TL * 48;
static constexpr size_t OFF_CT    = (size_t)TL * 64;
static constexpr size_t OFF_CT1   = (size_t)TL * 192;

typedef _Float16 h2 __attribute__((ext_vector_type(2)));
typedef _Float16 h8 __attribute__((ext_vector_type(8)));
typedef float f32x4 __attribute__((ext_vector_type(4)));

struct Params {
  const float* lm;  const float* lv;  const float* Tin;
  const float* cw0; const float* cb0; const float* cw1; const float* cb1; const float* cw2; const float* cb2;
  const float* pw0; const float* pb0; const float* pw1; const float* pb1; const float* pw2; const float* pb2;
  const float* fmw1; const float* fmb1; const float* fmw2; const float* fmb2;
  const float* fvw1; const float* fvb1; const float* fvw2; const float* fvb2;
  const float* lw0; const float* lb0; const float* lw1; const float* lb1; const float* lw2; const float* lb2;
  const float* w12src;   // precomputed w12/b12 in d_ws, or nullptr
  float* out;
};

__device__ __forceinline__ const float4* rc4(const float* p) { return reinterpret_cast<const float4*>(p); }
__device__ __forceinline__ float4*       rw4(float* p)       { return reinterpret_cast<float4*>(p); }

__device__ __forceinline__ void load8(const float* __restrict__ src, float* dst) {
  float4 a = rc4(src)[0], b = rc4(src)[1];
  dst[0]=a.x; dst[1]=a.y; dst[2]=a.z; dst[3]=a.w;
  dst[4]=b.x; dst[5]=b.y; dst[6]=b.z; dst[7]=b.w;
}
__device__ __forceinline__ void store8(float* __restrict__ dst, const float* v) {
  rw4(dst)[0] = make_float4(v[0],v[1],v[2],v[3]);
  rw4(dst)[1] = make_float4(v[4],v[5],v[6],v[7]);
}
__device__ __forceinline__ void store16(float* __restrict__ dst, const float* v) {
  rw4(dst)[0] = make_float4(v[0],v[1],v[2],v[3]);
  rw4(dst)[1] = make_float4(v[4],v[5],v[6],v[7]);
  rw4(dst)[2] = make_float4(v[8],v[9],v[10],v[11]);
  rw4(dst)[3] = make_float4(v[12],v[13],v[14],v[15]);
}

union U4 { uint32_t u[4]; h2 h[4]; h8 v; uint4 q; };

__device__ __forceinline__ h2 pack2(float a, float b) {
  h2 r; r[0] = (_Float16)a; r[1] = (_Float16)b; return r;
}

// ---- prep: collapse decoder layers 1+2 (linear compose; no relu between them)
__global__ __launch_bounds__(256) void tld_prep(const float* __restrict__ lw1,
                                                const float* __restrict__ lw2,
                                                const float* __restrict__ lb1,
                                                const float* __restrict__ lb2,
                                                float* __restrict__ ws) {
  const int tid = threadIdx.x;
  #pragma unroll 1
  for (int i = tid; i < 1024; i += 256) {
    int n = i >> 6, h = i & 63;
    float s = 0.f;
    #pragma unroll 8
    for (int o = 0; o < 64; ++o)
      s = fmaf(lw1[n * 4096 + h * 64 + o], lw2[n * 64 + o], s);
    ws[i] = s;
  }
  if (tid < 16) {
    float b = lb2[tid];
    #pragma unroll 8
    for (int o = 0; o < 64; ++o)
      b = fmaf(lb1[tid * 64 + o], lw2[tid * 64 + o], b);
    ws[1024 + tid] = b;
  }
}

__global__ __launch_bounds__(256, 4) void tld_fused(Params p) {
  // 40,576 B total -> 4 blocks/CU (160 KiB pool)
  __shared__ __align__(16) _Float16 s_W[2][64 * 40];   // 10,240 B  Wt[j][k] f16, row pad 40
  __shared__ __align__(16) float    s_w12[1024];       //  4,096 B
  __shared__ __align__(16) float    s_b12[16];
  __shared__ __align__(16) float    s_lb0[1024];       //  4,096 B
  // phase-1 weights overlaid with decode result buffer (union via pool):
  __shared__ __align__(16) char     s_pool[22080];

  float* s_hw1t = (float*)s_pool;             // [2][1024] head W1^T [o][f]
  float* s_hw2  = (float*)(s_pool + 8192);    // [2][1024] head W2 [o][j]
  float* s_hb1  = (float*)(s_pool + 16384);   // [2][128]
  float* s_hb2  = (float*)(s_pool + 17408);   // [2][8]
  float* s_ew2t = (float*)(s_pool + 17472);   // [128][8]  pw2^T
  float* s_eb2b = (float*)(s_pool + 21568);   // [128]     pb2
  _Float16* s_resh = (_Float16*)s_pool;       // decode: [4 waves][16 n][68] h16 (8704 B)

  const int tid = threadIdx.x;
  const int B   = blockIdx.x * 128;

  // ================= block staging =================
  rw4(s_lb0)[tid]          = rc4(p.lb0)[tid];
  rw4(s_hw2)[tid]          = rc4(p.fmw2)[tid];
  rw4(s_hw2 + 1024)[tid]   = rc4(p.fvw2)[tid];
  if (tid < 32)       { rw4(s_hb1)[tid] = rc4(p.fmb1)[tid]; }
  else if (tid < 64)  { rw4(s_hb1 + 128)[tid - 32] = rc4(p.fvb1)[tid - 32]; }
  else if (tid < 96)  { rw4(s_eb2b)[tid - 64] = rc4(p.pb2)[tid - 64]; }
  else if (tid < 100) { int q = tid - 96; rw4(s_hb2 + (q >> 1) * 8)[q & 1] = rc4((q >> 1) ? p.fvb2 : p.fmb2)[q & 1]; }
  #pragma unroll 1
  for (int i = tid; i < 2048; i += 256) {     // transpose head W1 -> [o][f]
    int r = i >> 10, ii = i & 1023, o = ii >> 3, f = ii & 7;
    s_hw1t[r * 1024 + ii] = (r ? p.fvw1 : p.fmw1)[f * 128 + o];
  }
  if (tid < 128) {                            // transpose pw2 -> [nk][i]
    #pragma unroll
    for (int i = 0; i < 8; ++i) s_ew2t[tid * 8 + i] = p.pw2[i * 128 + tid];
  }
  if (p.w12src) {
    rw4(s_w12)[tid] = rc4(p.w12src)[tid];
    if (tid < 4) rw4(s_b12)[tid] = rc4(p.w12src + 1024)[tid];
  } else {
    #pragma unroll 1
    for (int i = tid; i < 1024; i += 256) {
      int n = i >> 6, h = i & 63;
      float s = 0.f;
      for (int o = 0; o < 64; ++o)
        s = fmaf(p.lw1[n * 4096 + h * 64 + o], p.lw2[n * 64 + o], s);
      s_w12[i] = s;
    }
    if (tid < 16) {
      float b = p.lb2[tid];
      for (int o = 0; o < 64; ++o)
        b = fmaf(p.lb1[tid * 64 + o], p.lw2[tid * 64 + o], b);
      s_b12[tid] = b;
    }
  }
  // W node 0 -> f16 transposed LDS (thread: k = tid&31, j0 = (tid>>5)*8)
  const int wk  = tid & 31;
  const int wj0 = (tid >> 5) * 8;
  {
    const float4* g = rc4(p.lw0);
    float4 wa = g[wk * 16 + (tid >> 5) * 2];
    float4 wb = g[wk * 16 + (tid >> 5) * 2 + 1];
    _Float16* dW = s_W[0];
    dW[(wj0 + 0) * 40 + wk] = (_Float16)wa.x;
    dW[(wj0 + 1) * 40 + wk] = (_Float16)wa.y;
    dW[(wj0 + 2) * 40 + wk] = (_Float16)wa.z;
    dW[(wj0 + 3) * 40 + wk] = (_Float16)wa.w;
    dW[(wj0 + 4) * 40 + wk] = (_Float16)wb.x;
    dW[(wj0 + 5) * 40 + wk] = (_Float16)wb.y;
    dW[(wj0 + 6) * 40 + wk] = (_Float16)wb.z;
    dW[(wj0 + 7) * 40 + wk] = (_Float16)wb.w;
  }
  __syncthreads();

  // ================= phase 1 =================
  const int u    = tid & 127;
  const int t    = B + u;
  const int role = __builtin_amdgcn_readfirstlane((int)(tid >> 7));
  const float Tt = p.Tin[t];

  if (role == 0) {
    // f64 path: <0.1 binarization must match f64-resolved reference (round-1 fail)
    double e0d[8], e1d[8];
    const double Td = (double)Tt;
    #pragma unroll
    for (int j = 0; j < 8; ++j) {
      double v = Td * (double)p.cw0[j] + (double)p.cb0[j];
      e0d[j] = v < 0.0 ? 0.01 * v : v;
    }
    #pragma unroll
    for (int j = 0; j < 8; ++j) {
      double v = (double)p.cb1[j];
      #pragma unroll
      for (int i = 0; i < 8; ++i) v = fma(e0d[i], (double)p.cw1[i * 8 + j], v);
      e1d[j] = v < 0.0 ? 0.01 * v : v;
    }
    #pragma unroll 1
    for (int n2 = 0; n2 < 8; ++n2) {          // node pairs -> full 64B line stores
      float cb[16];
      #pragma unroll
      for (int kk = 0; kk < 16; ++kk) {
        const int nk = n2 * 16 + kk;
        double s = (double)p.cb2[nk];
        #pragma unroll
        for (int i = 0; i < 8; ++i)
          s = fma(e1d[i], (double)p.cw2[i * 128 + nk], s);
        cb[kk] = (s < 0.1) ? 0.f : 1.f;
      }
      store16(p.out + OFF_CT + (size_t)t * 128 + n2 * 16, cb);
    }
  } else {
    float e0[8], e1f[8];
    #pragma unroll
    for (int j = 0; j < 8; ++j) {
      float v = fmaf(Tt, p.pw0[j], p.pb0[j]);
      e0[j] = v < 0.f ? 0.01f * v : v;
    }
    #pragma unroll
    for (int j = 0; j < 8; ++j) {
      float v = p.pb1[j];
      #pragma unroll
      for (int i = 0; i < 8; ++i) v = fmaf(e0[i], p.pw1[i * 8 + j], v);
      e1f[j] = v < 0.f ? 0.01f * v : v;
    }
    #pragma unroll 1
    for (int n2 = 0; n2 < 8; ++n2) {
      float cb[16];
      #pragma unroll
      for (int kk = 0; kk < 16; ++kk) {
        const int nk = n2 * 16 + kk;
        const float4* w = (const float4*)&s_ew2t[nk * 8];
        float4 x0 = w[0], x1 = w[1];
        float s = s_eb2b[nk];
        s = fmaf(e1f[0], x0.x, s); s = fmaf(e1f[1], x0.y, s);
        s = fmaf(e1f[2], x0.z, s); s = fmaf(e1f[3], x0.w, s);
        s = fmaf(e1f[4], x1.x, s); s = fmaf(e1f[5], x1.y, s);
        s = fmaf(e1f[6], x1.z, s); s = fmaf(e1f[7], x1.w, s);
        cb[kk] = s;
      }
      store16(p.out + OFF_CT1 + (size_t)t * 128 + n2 * 16, cb);
    }
  }

  // ---- heads (LDS weights, shared across both layers)
  {
    float hx[2][8];
    if (role == 0) {
      load8(p.lm + (size_t)t * 8, hx[0]);
      load8(p.lm + (size_t)TL * 8 + (size_t)t * 8, hx[1]);
    } else {
      load8(p.lv + (size_t)t * 8, hx[0]);
      load8(p.lv + (size_t)TL * 8 + (size_t)t * 8, hx[1]);
    }
    const float* w1t  = s_hw1t + role * 1024;
    const float* w2r  = s_hw2  + role * 1024;
    const float* b1   = s_hb1  + role * 128;
    const float* hb2r = s_hb2  + role * 8;
    float acc8[2][8];
    #pragma unroll
    for (int l = 0; l < 2; ++l)
      #pragma unroll
      for (int j = 0; j < 8; ++j) acc8[l][j] = hb2r[j];
    #pragma unroll 1
    for (int o = 0; o < 128; ++o) {
      float4 u0 = rc4(w1t)[o * 2], u1 = rc4(w1t)[o * 2 + 1];
      const float wf[8] = {u0.x,u0.y,u0.z,u0.w,u1.x,u1.y,u1.z,u1.w};
      const float bo = b1[o];
      float a0 = bo, a1 = bo;
      #pragma unroll
      for (int f = 0; f < 8; ++f) {
        a0 = fmaf(hx[0][f], wf[f], a0);
        a1 = fmaf(hx[1][f], wf[f], a1);
      }
      a0 = fmaxf(a0, 0.f); a1 = fmaxf(a1, 0.f);
      float4 v0 = rc4(w2r)[o * 2], v1 = rc4(w2r)[o * 2 + 1];
      const float w2f[8] = {v0.x,v0.y,v0.z,v0.w,v1.x,v1.y,v1.z,v1.w};
      #pragma unroll
      for (int j = 0; j < 8; ++j) {
        acc8[0][j] = fmaf(a0, w2f[j], acc8[0][j]);
        acc8[1][j] = fmaf(a1, w2f[j], acc8[1][j]);
      }
    }
    const size_t hbase = role ? OFF_LVP : OFF_LMP;
    store8(p.out + hbase + (size_t)t * 8, acc8[0]);
    store8(p.out + hbase + (size_t)TL * 8 + (size_t)t * 8, acc8[1]);
  }

  // phase-1 global writes (Ct/Ct_1) must be visible to decode reads; pool reuse safe after this
  __syncthreads();

  // ================= decode: per-node f16 MFMA, swapped operands =================
  // waves 0-1: recon (C=Ct, src=t); waves 2-3: pred (C=Ct_1, src=t-1)
  // mfma(A=W^T frag, B=X^T frag): A[i=j][k]: j=l15(+16*ji), k=g*8+e
  //                               B[k][col=t]: t=l15, k=g*8+e
  //                               D[row=j=g*4+reg][col=t=l15]   (m89 layout, swapped)
  const int w     = tid >> 6;
  const int lane  = tid & 63;
  const int drole = __builtin_amdgcn_readfirstlane(w >> 1);
  const int tl0   = (w & 1) * 64;
  const int l15   = lane & 15;
  const int g     = lane >> 4;
  const int kb    = (g & 1) * 4;               // k-slab base within lm/lv
  const float* xbase = (g < 2) ? p.lm : p.lv;  // g 0,1 -> lm pairs; g 2,3 -> lv pairs
  const float* Cbuf  = p.out + (drole ? OFF_CT1 : OFF_CT);
  _Float16* resw = s_resh + w * 1088;          // [16 n][68]

  // node-invariant latent pair fragments (held in 16 VGPRs)
  int trow[4];
  U4 dv[4];
  #pragma unroll
  for (int ti = 0; ti < 4; ++ti) {
    trow[ti] = B + tl0 + ti * 16 + l15;
    const int src = trow[ti] - drole;          // pred uses t-1
    const int s0  = src < 0 ? 0 : src;
    float4 v0 = rc4(xbase + (size_t)s0 * 8 + kb)[0];
    float4 v1 = rc4(xbase + (size_t)TL * 8 + (size_t)s0 * 8 + kb)[0];
    U4 dd;
    dd.h[0] = pack2(v0.x, v1.x);
    dd.h[1] = pack2(v0.y, v1.y);
    dd.h[2] = pack2(v0.z, v1.z);
    dd.h[3] = pack2(v0.w, v1.w);
    if (src < 0) dd.q = make_uint4(0u, 0u, 0u, 0u);
    dv[ti] = dd;
  }

  #pragma unroll 1
  for (int n = 0; n < 16; ++n) {
    float4 wa, wb;
    if (n < 15) {                              // T14: issue next node's W early
      const float4* gsrc = rc4(p.lw0 + (size_t)(n + 1) * 2048);
      wa = gsrc[wk * 16 + (tid >> 5) * 2];
      wb = gsrc[wk * 16 + (tid >> 5) * 2 + 1];
    }
    const _Float16* Wcur = s_W[n & 1];
    h8 Af0 = *(const h8*)&Wcur[( 0 + l15) * 40 + g * 8];
    h8 Af1 = *(const h8*)&Wcur[(16 + l15) * 40 + g * 8];
    h8 Af2 = *(const h8*)&Wcur[(32 + l15) * 40 + g * 8];
    h8 Af3 = *(const h8*)&Wcur[(48 + l15) * 40 + g * 8];
    const float b12n = s_b12[n];

    #pragma unroll
    for (int ti = 0; ti < 4; ++ti) {
      // gate: c values from the just-written C output (L2-hot, block-local rows)
      float4 cc = rc4(Cbuf + (size_t)trow[ti] * 128 + n * 8 + kb)[0];
      U4 bx;
      bx.h[0] = pack2(cc.x, cc.x) * dv[ti].h[0];
      bx.h[1] = pack2(cc.y, cc.y) * dv[ti].h[1];
      bx.h[2] = pack2(cc.z, cc.z) * dv[ti].h[2];
      bx.h[3] = pack2(cc.w, cc.w) * dv[ti].h[3];
      const h8 Bf = bx.v;

      float partial = 0.f;
      {
        float4 bias = rc4(s_lb0 + n * 64 +  0 + g * 4)[0];
        f32x4 d; d[0]=bias.x; d[1]=bias.y; d[2]=bias.z; d[3]=bias.w;
        d = __builtin_amdgcn_mfma_f32_16x16x32_f16(Af0, Bf, d, 0, 0, 0);
        float4 wv = rc4(s_w12 + n * 64 +  0 + g * 4)[0];
        partial = fmaf(fmaxf(d[0],0.f), wv.x, partial);
        partial = fmaf(fmaxf(d[1],0.f), wv.y, partial);
        partial = fmaf(fmaxf(d[2],0.f), wv.z, partial);
        partial = fmaf(fmaxf(d[3],0.f), wv.w, partial);
      }
      {
        float4 bias = rc4(s_lb0 + n * 64 + 16 + g * 4)[0];
        f32x4 d; d[0]=bias.x; d[1]=bias.y; d[2]=bias.z; d[3]=bias.w;
        d = __builtin_amdgcn_mfma_f32_16x16x32_f16(Af1, Bf, d, 0, 0, 0);
        float4 wv = rc4(s_w12 + n * 64 + 16 + g * 4)[0];
        partial = fmaf(fmaxf(d[0],0.f), wv.x, partial);
        partial = fmaf(fmaxf(d[1],0.f), wv.y, partial);
        partial = fmaf(fmaxf(d[2],0.f), wv.z, partial);
        partial = fmaf(fmaxf(d[3],0.f), wv.w, partial);
      }
      {
        float4 bias = rc4(s_lb0 + n * 64 + 32 + g * 4)[0];
        f32x4 d; d[0]=bias.x; d[1]=bias.y; d[2]=bias.z; d[3]=bias.w;
        d = __builtin_amdgcn_mfma_f32_16x16x32_f16(Af2, Bf, d, 0, 0, 0);
        float4 wv = rc4(s_w12 + n * 64 + 32 + g * 4)[0];
        partial = fmaf(fmaxf(d[0],0.f), wv.x, partial);
        partial = fmaf(fmaxf(d[1],0.f), wv.y, partial);
        partial = fmaf(fmaxf(d[2],0.f), wv.z, partial);
        partial = fmaf(fmaxf(d[3],0.f), wv.w, partial);
      }
      {
        float4 bias = rc4(s_lb0 + n * 64 + 48 + g * 4)[0];
        f32x4 d; d[0]=bias.x; d[1]=bias.y; d[2]=bias.z; d[3]=bias.w;
        d = __builtin_amdgcn_mfma_f32_16x16x32_f16(Af3, Bf, d, 0, 0, 0);
        float4 wv = rc4(s_w12 + n * 64 + 48 + g * 4)[0];
        partial = fmaf(fmaxf(d[0],0.f), wv.x, partial);
        partial = fmaf(fmaxf(d[1],0.f), wv.y, partial);
        partial = fmaf(fmaxf(d[2],0.f), wv.z, partial);
        partial = fmaf(fmaxf(d[3],0.f), wv.w, partial);
      }
      // reduce over the 4 g-groups (j quadrants): 2 shfl steps
      partial += __shfl_xor(partial, 16, 64);
      partial += __shfl_xor(partial, 32, 64);
      const float r = fmaxf(b12n + partial, 0.f);
      if (lane < 16) resw[n * 68 + ti * 16 + l15] = (_Float16)r;
    }

    // double-buffer: write next node's W (buffer (n+1)&1 last read in iter n-1,
    // all waves past that iter's barrier), then one barrier
    if (n < 15) {
      _Float16* dW = s_W[(n + 1) & 1];
      dW[(wj0 + 0) * 40 + wk] = (_Float16)wa.x;
      dW[(wj0 + 1) * 40 + wk] = (_Float16)wa.y;
      dW[(wj0 + 2) * 40 + wk] = (_Float16)wa.z;
      dW[(wj0 + 3) * 40 + wk] = (_Float16)wa.w;
      dW[(wj0 + 4) * 40 + wk] = (_Float16)wb.x;
      dW[(wj0 + 5) * 40 + wk] = (_Float16)wb.y;
      dW[(wj0 + 6) * 40 + wk] = (_Float16)wb.z;
      dW[(wj0 + 7) * 40 + wk] = (_Float16)wb.w;
    }
    __syncthreads();
  }

  // final store: lane owns t = B + tl0 + lane; gathers its 16 node results
  {
    float o16[16];
    #pragma unroll
    for (int n = 0; n < 16; ++n) o16[n] = (float)resw[n * 68 + lane];
    const size_t r_off = drole ? OFF_PRED : OFF_RECON;
    store16(p.out + r_off + (size_t)(B + tl0 + lane) * 16, o16);
  }
}

extern "C" void kernel_launch(void* const* d_in, const int* in_sizes, int n_in,
                              void* d_out, int out_size, void* d_ws, size_t ws_size,
                              hipStream_t stream) {
  Params p;
  p.lm   = (const float*)d_in[0];
  p.lv   = (const float*)d_in[1];
  p.Tin  = (const float*)d_in[2];
  p.cw0  = (const float*)d_in[3];  p.cb0 = (const float*)d_in[4];
  p.cw1  = (const float*)d_in[5];  p.cb1 = (const float*)d_in[6];
  p.cw2  = (const float*)d_in[7];  p.cb2 = (const float*)d_in[8];
  p.pw0  = (const float*)d_in[9];  p.pb0 = (const float*)d_in[10];
  p.pw1  = (const float*)d_in[11]; p.pb1 = (const float*)d_in[12];
  p.pw2  = (const float*)d_in[13]; p.pb2 = (const float*)d_in[14];
  p.fmw1 = (const float*)d_in[15]; p.fmb1 = (const float*)d_in[16];
  p.fmw2 = (const float*)d_in[17]; p.fmb2 = (const float*)d_in[18];
  p.fvw1 = (const float*)d_in[19]; p.fvb1 = (const float*)d_in[20];
  p.fvw2 = (const float*)d_in[21]; p.fvb2 = (const float*)d_in[22];
  p.lw0  = (const float*)d_in[23]; p.lb0 = (const float*)d_in[24];
  p.lw1  = (const float*)d_in[25]; p.lb1 = (const float*)d_in[26];
  p.lw2  = (const float*)d_in[27]; p.lb2 = (const float*)d_in[28];
  p.out  = (float*)d_out;

  const bool use_ws = ws_size >= 1040 * sizeof(float);
  if (use_ws) {
    tld_prep<<<dim3(1), dim3(256), 0, stream>>>(p.lw1, p.lw2, p.lb1, p.lb2, (float*)d_ws);
    p.w12src = (const float*)d_ws;
  } else {
    p.w12src = nullptr;
  }
  tld_fused<<<dim3(TL / 128), dim3(256), 0, stream>>>(p);
}